// Round 17
// baseline (71.343 us; speedup 1.0000x reference)
//
#include <hip/hip_runtime.h>
#include <math.h>

typedef __bf16 bf16x8 __attribute__((ext_vector_type(8)));
typedef float  f32x4  __attribute__((ext_vector_type(4)));

#define NT2 12    // partial slots per row = (D/BN=6) * 2 wave-columns

__device__ inline float gelu_f(float x) {
    return 0.5f * x * (1.0f + erff(x * 0.70710678118654752f));
}

// global -> LDS direct copy, 16 B per lane (HW: wave-uniform LDS base + lane*16)
typedef const __attribute__((address_space(1))) void* gas_t;
typedef __attribute__((address_space(3))) void*       las_t;
__device__ __forceinline__ void gl_lds16(const void* g, void* l) {
    __builtin_amdgcn_global_load_lds((gas_t)g, (las_t)l, 16, 0, 0);
}

// ---------------------------------------------------------------------------
// S0W: W1 (fp32 [K][N]) -> transposed bf16 (RTN): W1t[n*K + k].
// ---------------------------------------------------------------------------
__global__ __launch_bounds__(256) void s0_w1t(
    const float* __restrict__ W1, __bf16* __restrict__ Wt, int Dn)
{
    __shared__ float tile[32][33];
    const int k0 = blockIdx.x * 32;
    const int n0 = blockIdx.y * 32;
    const int tx = threadIdx.x & 31, ty = threadIdx.x >> 5;
    #pragma unroll
    for (int p = 0; p < 4; ++p)
        tile[ty + p * 8][tx] = W1[(size_t)(k0 + ty + p * 8) * Dn + n0 + tx];
    __syncthreads();
    #pragma unroll
    for (int p = 0; p < 4; ++p) {
        const int n = n0 + ty + p * 8, k = k0 + tx;
        Wt[(size_t)n * Dn + k] = (__bf16)tile[tx][ty + p * 8];
    }
}

__device__ __forceinline__ bf16x8 cvt8(const float4& lo, const float4& hi) {
    bf16x8 ab;
    ab[0] = (__bf16)lo.x; ab[1] = (__bf16)lo.y;
    ab[2] = (__bf16)lo.z; ab[3] = (__bf16)lo.w;
    ab[4] = (__bf16)hi.x; ab[5] = (__bf16)hi.y;
    ab[6] = (__bf16)hi.z; ab[7] = (__bf16)hi.w;
    return ab;
}

// ---------------------------------------------------------------------------
// K1: round-14 base (128x128 tile, BK=32, 8 waves 4x2, 2-phase dbuf,
// A reg->cvt->ds_write / B gl_lds direct, XOR swizzle both sides) with
// 2-DEEP A REGISTER PREFETCH: A(kt+2) loads issue a full iteration before
// their cvt (two named reg sets, step-2 unrolled loop -> static indexing).
// Logits bit-identical to rounds 8-16 (same values, same order).
// ---------------------------------------------------------------------------
__global__ __launch_bounds__(512) void k1_p2(
    const float* __restrict__ X, const __bf16* __restrict__ W1t,
    const float* __restrict__ b1, const float* __restrict__ W2,
    float* __restrict__ partial, int Kd)
{
    __shared__ __bf16 Ash[2][128 * 32];   // bf16 A tile, 8 KB per buffer
    __shared__ __bf16 Bsh[2][128 * 32];   // bf16 B tile, 8 KB per buffer

    const int t    = threadIdx.x;
    const int lane = t & 63;
    const int w    = t >> 6;          // 0..7
    const int wr   = w >> 1;          // 0..3: 32-row band
    const int wc   = w & 1;           // 0..1: 64-col band
    const int ln15 = lane & 15, lg = lane >> 4;
    const int m0   = blockIdx.x * 128;
    const int n0   = blockIdx.y * 128;

    // A staging: thread owns row r = t>>2, chunk q = t&3 (8 fp32 -> 8 bf16)
    const int ar  = t >> 2, aq = t & 3;
    const float* gA = X + (size_t)(m0 + ar) * Kd + aq * 8;
    const int    awr = ar * 32 + (aq ^ ((ar >> 1) & 3)) * 8;

    // B staging: 512 chunks (16 B = 8 bf16); thread stages chunk t.
    const int brow = t >> 2;
    const int bkw  = (t & 3) ^ ((brow >> 1) & 3);
    const __bf16* gB = W1t + (size_t)(n0 + brow) * Kd + bkw * 8;

    // fragment LDS offsets (constant across k-loop)
    int aoff[2], boff[4];
    #pragma unroll
    for (int mf = 0; mf < 2; ++mf) {
        const int r = wr * 32 + mf * 16 + ln15;
        aoff[mf] = r * 32 + (lg ^ ((r >> 1) & 3)) * 8;
    }
    #pragma unroll
    for (int nf = 0; nf < 4; ++nf) {
        const int r = wc * 64 + nf * 16 + ln15;
        boff[nf] = r * 32 + (lg ^ ((r >> 1) & 3)) * 8;
    }

    f32x4 acc[2][4];
    #pragma unroll
    for (int i = 0; i < 2; ++i)
        #pragma unroll
        for (int j = 0; j < 4; ++j)
            acc[i][j] = (f32x4){0.f, 0.f, 0.f, 0.f};

    const int nt = Kd / 32;   // 24 (even)

    // ---- prologue: stage tile 0 into buf 0; preload A(1) into set0 ----
    float4 alo0, ahi0, alo1, ahi1;
    {
        const float4 lo = *(const float4*)(gA);
        const float4 hi = *(const float4*)(gA + 4);
        *(bf16x8*)&Ash[0][awr] = cvt8(lo, hi);
        gl_lds16(gB, &Bsh[0][t * 8]);
        alo0 = *(const float4*)(gA + 32);      // A(1), consumed next iter
        ahi0 = *(const float4*)(gA + 36);
    }
    __syncthreads();

    #define MFMA_PHASE(BUF)                                                     \
        {                                                                       \
            bf16x8 fa[2], fb[4];                                                \
            _Pragma("unroll")                                                   \
            for (int mf = 0; mf < 2; ++mf)                                      \
                fa[mf] = *(const bf16x8*)&Ash[BUF][aoff[mf]];                   \
            _Pragma("unroll")                                                   \
            for (int nf = 0; nf < 4; ++nf)                                      \
                fb[nf] = *(const bf16x8*)&Bsh[BUF][boff[nf]];                   \
            _Pragma("unroll")                                                   \
            for (int mf = 0; mf < 2; ++mf)                                      \
                _Pragma("unroll")                                               \
                for (int nf = 0; nf < 4; ++nf)                                  \
                    acc[mf][nf] = __builtin_amdgcn_mfma_f32_16x16x32_bf16(      \
                        fa[mf], fb[nf], acc[mf][nf], 0, 0, 0);                  \
        }

    for (int kt = 0; kt < nt; kt += 2) {
        // ---- half 1: compute buf0 (tile kt); prep buf1 (tile kt+1) ----
        if (kt + 2 < nt) {                     // load A(kt+2) -> set1 (deep)
            alo1 = *(const float4*)(gA + (kt + 2) * 32);
            ahi1 = *(const float4*)(gA + (kt + 2) * 32 + 4);
        }
        gl_lds16(gB + (kt + 1) * 32, &Bsh[1][t * 8]);   // B(kt+1)
        MFMA_PHASE(0)
        *(bf16x8*)&Ash[1][awr] = cvt8(alo0, ahi0);      // A(kt+1) from set0
        __syncthreads();

        // ---- half 2: compute buf1 (tile kt+1); prep buf0 (tile kt+2) ----
        if (kt + 3 < nt) {                     // load A(kt+3) -> set0 (deep)
            alo0 = *(const float4*)(gA + (kt + 3) * 32);
            ahi0 = *(const float4*)(gA + (kt + 3) * 32 + 4);
        }
        if (kt + 2 < nt)
            gl_lds16(gB + (kt + 2) * 32, &Bsh[0][t * 8]);   // B(kt+2)
        MFMA_PHASE(1)
        if (kt + 2 < nt)
            *(bf16x8*)&Ash[0][awr] = cvt8(alo1, ahi1);      // A(kt+2) from set1
        __syncthreads();
    }
    #undef MFMA_PHASE

    // ---- epilogue: per-row sum of gelu(c + b1)*W2 over this wave's 64 cols ----
    float b1v[4], w2v[4];
    #pragma unroll
    for (int nf = 0; nf < 4; ++nf) {
        const int n = n0 + wc * 64 + nf * 16 + ln15;
        b1v[nf] = b1[n];
        w2v[nf] = W2[n];
    }
    #pragma unroll
    for (int mf = 0; mf < 2; ++mf)
        #pragma unroll
        for (int j = 0; j < 4; ++j) {
            float s = 0.f;
            #pragma unroll
            for (int nf = 0; nf < 4; ++nf) {
                float c = acc[mf][nf][j] + b1v[nf];
                s += gelu_f(c) * w2v[nf];
            }
            s += __shfl_xor(s, 1);
            s += __shfl_xor(s, 2);
            s += __shfl_xor(s, 4);
            s += __shfl_xor(s, 8);
            if (ln15 == 0) {
                const int m = m0 + wr * 32 + mf * 16 + lg * 4 + j;
                partial[(size_t)m * NT2 + blockIdx.y * 2 + wc] = s;
            }
        }
}

// ---------------------------------------------------------------------------
// K2a: M-parallel logits + probs. One thread per position; 12 contiguous
// partial loads. 64 blocks -> latency covered by TLP.
// ---------------------------------------------------------------------------
__global__ __launch_bounds__(256) void k2a_logits(
    const float* __restrict__ partial, const float* __restrict__ lengths,
    const float* __restrict__ b2p, float* __restrict__ logits,
    float* __restrict__ out_probs, int S)
{
    const int idx = blockIdx.x * 256 + threadIdx.x;
    const int b = idx / S, s = idx - b * S;
    float sum = b2p[0];
    #pragma unroll
    for (int jt = 0; jt < NT2; ++jt)
        sum += partial[(size_t)idx * NT2 + jt];
    logits[idx] = sum;
    const int len = (int)(lengths[b] * (float)S);
    out_probs[idx] = (s < len) ? 1.0f / (1.0f + expf(-sum)) : 0.0f;
}

// ---------------------------------------------------------------------------
// K2b: per-batch flags (logit>0, last_valid=1); scan -> bpos; nb/short/lens.
// ---------------------------------------------------------------------------
__global__ __launch_bounds__(256) void k2b_scan(
    const float* __restrict__ logits, const float* __restrict__ lengths,
    float* __restrict__ out_short, float* __restrict__ out_nb,
    float* __restrict__ out_lens, int* __restrict__ bpos,
    int* __restrict__ nb_arr, int S, int K)
{
    const int b = blockIdx.x;
    const int t = threadIdx.x;
    const int len = (int)(lengths[b] * (float)S);

    __shared__ int cnt[256];
    __shared__ int flags_s[2048];

    const int RP = S / 256;
    const int base_s = t * RP;
    int local = 0;
    #pragma unroll
    for (int r = 0; r < 8; ++r) {
        int s = base_s + r;
        bool v = (s < len);
        int f = (s == len - 1) ? 1 : ((v && logits[(size_t)b * S + s] > 0.0f) ? 1 : 0);
        flags_s[s] = f;
        local += f;
    }
    cnt[t] = local;
    __syncthreads();
    for (int off = 1; off < 256; off <<= 1) {
        int v = cnt[t];
        int u = (t >= off) ? cnt[t - off] : 0;
        __syncthreads();
        cnt[t] = v + u;
        __syncthreads();
    }
    int excl = cnt[t] - local;
    int total = cnt[255];
    for (int r = 0; r < RP; ++r) {
        int s = base_s + r;
        if (flags_s[s]) { bpos[b * S + excl] = s; ++excl; }
    }
    if (t == 0) {
        nb_arr[b] = total;
        float nbf = (float)total;
        float Kf  = (float)K;
        out_nb[b]   = nbf;
        out_lens[b] = (float)len;
        float sh;
        if (nbf >= Kf - 1.0f)      sh = 1.0f;
        else if (nbf > 0.0f)       sh = (nbf + 1.0f) / Kf;
        else                       sh = 0.0f;
        out_short[b] = sh;
    }
}

// ---------------------------------------------------------------------------
// K3: segment-mean pooling from fp32 X. One block per (b,k).
// ---------------------------------------------------------------------------
__global__ __launch_bounds__(192) void k3_pool(
    const float* __restrict__ X, const int* __restrict__ bpos,
    const int* __restrict__ nb_arr, float* __restrict__ pooled,
    int S, int D, int K)
{
    const int bk = blockIdx.x;
    const int b  = bk / K;
    const int k  = bk - b * K;
    const int t  = threadIdx.x;
    const int nb = nb_arr[b];

    float4 acc = {0.f, 0.f, 0.f, 0.f};
    if (k < nb) {
        int start = (k == 0) ? 0 : (bpos[b * S + k - 1] + 1);
        int end   = bpos[b * S + k] + 1;
        float cntf = (float)(end - start);
        for (int s = start; s < end; ++s) {
            const float4 v = *(const float4*)&X[((size_t)b * S + s) * D + t * 4];
            acc.x += v.x; acc.y += v.y; acc.z += v.z; acc.w += v.w;
        }
        acc.x /= cntf; acc.y /= cntf; acc.z /= cntf; acc.w /= cntf;
    }
    *(float4*)&pooled[((size_t)b * K + k) * D + t * 4] = acc;
}

// ---------------------------------------------------------------------------
extern "C" void kernel_launch(void* const* d_in, const int* in_sizes, int n_in,
                              void* d_out, int out_size, void* d_ws, size_t ws_size,
                              hipStream_t stream) {
    const float* hidden  = (const float*)d_in[0];
    const float* lengths = (const float*)d_in[1];
    const float* W1      = (const float*)d_in[2];
    const float* b1      = (const float*)d_in[3];
    const float* W2      = (const float*)d_in[4];
    const float* b2      = (const float*)d_in[5];

    const int B = in_sizes[1];
    const int D = in_sizes[3];
    const int S = in_sizes[0] / (B * D);
    const int M = B * S;
    const int K = (out_size - B * S - 3 * B) / (B * D);

    float* out_pooled = (float*)d_out;
    float* out_probs  = out_pooled + (size_t)B * K * D;
    float* out_short  = out_probs + (size_t)B * S;
    float* out_nb     = out_short + B;
    float* out_lens   = out_nb + B;

    // d_ws: partial (786 KB) + logits (64 KB) + bpos (64 KB) + nb_arr
    char* wsp = (char*)d_ws;
    float* partial = (float*)wsp; wsp += (size_t)M * NT2 * sizeof(float);
    float* logits  = (float*)wsp; wsp += (size_t)M * sizeof(float);
    int*   bpos    = (int*)wsp;   wsp += (size_t)M * sizeof(int);
    int*   nb_arr  = (int*)wsp;

    // bf16 W1^T lives in the pooled output region (K3 overwrites it at the end).
    __bf16* W1t = (__bf16*)out_pooled;

    dim3 gs(D / 32, D / 32);
    s0_w1t<<<gs, 256, 0, stream>>>(W1, W1t, D);

    dim3 g1(M / 128, D / 128);
    k1_p2<<<g1, 512, 0, stream>>>(hidden, W1t, b1, W2, partial, D);

    k2a_logits<<<M / 256, 256, 0, stream>>>(partial, lengths, b2, logits,
                                            out_probs, S);
    k2b_scan<<<B, 256, 0, stream>>>(logits, lengths, out_short, out_nb,
                                    out_lens, bpos, nb_arr, S, K);
    k3_pool<<<B * K, D / 4, 0, stream>>>(hidden, bpos, nb_arr, out_pooled, S, D, K);
}

// Round 18
// 69.062 us; speedup vs baseline: 1.0330x; 1.0330x over previous
//
#include <hip/hip_runtime.h>
#include <math.h>

typedef __bf16 bf16x8 __attribute__((ext_vector_type(8)));
typedef float  f32x4  __attribute__((ext_vector_type(4)));

#define NT2 12    // partial slots per row = (D/BN=6) * 2 wave-columns

__device__ inline float gelu_f(float x) {
    return 0.5f * x * (1.0f + erff(x * 0.70710678118654752f));
}

// global -> LDS direct copy, 16 B per lane (HW: wave-uniform LDS base + lane*16)
typedef const __attribute__((address_space(1))) void* gas_t;
typedef __attribute__((address_space(3))) void*       las_t;
__device__ __forceinline__ void gl_lds16(const void* g, void* l) {
    __builtin_amdgcn_global_load_lds((gas_t)g, (las_t)l, 16, 0, 0);
}

// ---------------------------------------------------------------------------
// S0W: W1 (fp32 [K][N]) -> transposed bf16 (RTN): W1t[n*K + k].
// ---------------------------------------------------------------------------
__global__ __launch_bounds__(256) void s0_w1t(
    const float* __restrict__ W1, __bf16* __restrict__ Wt, int Dn)
{
    __shared__ float tile[32][33];
    const int k0 = blockIdx.x * 32;
    const int n0 = blockIdx.y * 32;
    const int tx = threadIdx.x & 31, ty = threadIdx.x >> 5;
    #pragma unroll
    for (int p = 0; p < 4; ++p)
        tile[ty + p * 8][tx] = W1[(size_t)(k0 + ty + p * 8) * Dn + n0 + tx];
    __syncthreads();
    #pragma unroll
    for (int p = 0; p < 4; ++p) {
        const int n = n0 + ty + p * 8, k = k0 + tx;
        Wt[(size_t)n * Dn + k] = (__bf16)tile[tx][ty + p * 8];
    }
}

// ---------------------------------------------------------------------------
// S0X: X fp32 -> bf16 (RTN), streaming at HBM BW.
// ---------------------------------------------------------------------------
__global__ __launch_bounds__(256) void s0_xb(
    const float* __restrict__ X, __bf16* __restrict__ Xb, int n8)
{
    const int i = blockIdx.x * 256 + threadIdx.x;
    if (i < n8) {
        const float4 v0 = *(const float4*)(X + (size_t)i * 8);
        const float4 v1 = *(const float4*)(X + (size_t)i * 8 + 4);
        bf16x8 o;
        o[0] = (__bf16)v0.x; o[1] = (__bf16)v0.y;
        o[2] = (__bf16)v0.z; o[3] = (__bf16)v0.w;
        o[4] = (__bf16)v1.x; o[5] = (__bf16)v1.y;
        o[6] = (__bf16)v1.z; o[7] = (__bf16)v1.w;
        *(bf16x8*)(Xb + (size_t)i * 8) = o;
    }
}

// ---------------------------------------------------------------------------
// K1: bf16 MFMA GEMM, 128x128 tile, BK=32, 8 waves (4x2, 32x64 each),
// COUNTED-VMCNT 3-BUFFER PIPELINE (T3/T4): per iter
//   [s_waitcnt vmcnt(2); s_barrier; sched_barrier; ds_read+MFMA;
//    issue tile kt+2 (2x gl_lds) -> buf (kt+2)%3]
// Tile k+2's loads stay in flight across TWO barriers (no vmcnt(0) drain —
// __syncthreads is replaced by raw s_barrier). Safety: all waves run the
// same discipline, so barrier-exit => every wave's tile-k chunks landed;
// buffer (kt+2)%3 last held tile kt-1, whose reads finished before the
// barrier all waves just passed. Tail: clamped dummy issues keep the
// vmcnt arithmetic uniform; vmcnt(0) drain before kernel end.
// Staging/fragment mapping identical to rounds 11-12 -> logits bit-identical
// (absmax checksum 7.039062).
// ---------------------------------------------------------------------------
__global__ __launch_bounds__(512) void k1_p3(
    const __bf16* __restrict__ Xb, const __bf16* __restrict__ W1t,
    const float* __restrict__ b1, const float* __restrict__ W2,
    float* __restrict__ partial, int Kd)
{
    __shared__ __bf16 Ash[3][128 * 32];   // 8 KB per buffer
    __shared__ __bf16 Bsh[3][128 * 32];

    const int t    = threadIdx.x;
    const int lane = t & 63;
    const int w    = t >> 6;          // 0..7
    const int wr   = w >> 1;          // 0..3: 32-row band
    const int wc   = w & 1;           // 0..1: 64-col band
    const int ln15 = lane & 15, lg = lane >> 4;
    const int m0   = blockIdx.x * 128;
    const int n0   = blockIdx.y * 128;

    // staging: thread t owns LDS chunk t (16 B) of A and of B.
    const int srow = t >> 2;                       // 0..127
    const int sgkw = (t & 3) ^ ((srow >> 1) & 3);  // source-swizzled chunk
    const __bf16* gA = Xb  + (size_t)(m0 + srow) * Kd + sgkw * 8;
    const __bf16* gB = W1t + (size_t)(n0 + srow) * Kd + sgkw * 8;

    // fragment LDS offsets (constant across k-loop)
    int aoff[2], boff[4];
    #pragma unroll
    for (int mf = 0; mf < 2; ++mf) {
        const int r = wr * 32 + mf * 16 + ln15;
        aoff[mf] = r * 32 + (lg ^ ((r >> 1) & 3)) * 8;
    }
    #pragma unroll
    for (int nf = 0; nf < 4; ++nf) {
        const int r = wc * 64 + nf * 16 + ln15;
        boff[nf] = r * 32 + (lg ^ ((r >> 1) & 3)) * 8;
    }

    f32x4 acc[2][4];
    #pragma unroll
    for (int i = 0; i < 2; ++i)
        #pragma unroll
        for (int j = 0; j < 4; ++j)
            acc[i][j] = (f32x4){0.f, 0.f, 0.f, 0.f};

    // ---- prologue: issue tiles 0 and 1 (2 gl_lds each) ----
    gl_lds16(gA,      &Ash[0][t * 8]);
    gl_lds16(gB,      &Bsh[0][t * 8]);
    gl_lds16(gA + 32, &Ash[1][t * 8]);
    gl_lds16(gB + 32, &Bsh[1][t * 8]);
    // outstanding: 4 (tiles 0,1)

    const int nt = Kd / 32;   // 24
    for (int kt = 0; kt < nt; ++kt) {
        // wait MY tile-kt pair (leave later tiles in flight), then sync.
        asm volatile("s_waitcnt vmcnt(2)" ::: "memory");
        __builtin_amdgcn_s_barrier();
        __builtin_amdgcn_sched_barrier(0);

        const int cb = kt % 3;
        bf16x8 fa[2], fb[4];
        #pragma unroll
        for (int mf = 0; mf < 2; ++mf)
            fa[mf] = *(const bf16x8*)&Ash[cb][aoff[mf]];
        #pragma unroll
        for (int nf = 0; nf < 4; ++nf)
            fb[nf] = *(const bf16x8*)&Bsh[cb][boff[nf]];
        #pragma unroll
        for (int mf = 0; mf < 2; ++mf)
            #pragma unroll
            for (int nf = 0; nf < 4; ++nf)
                acc[mf][nf] = __builtin_amdgcn_mfma_f32_16x16x32_bf16(
                    fa[mf], fb[nf], acc[mf][nf], 0, 0, 0);

        // issue tile kt+2 (clamped dummy at tail keeps vmcnt uniform)
        const int kn = (kt + 2 < nt) ? (kt + 2) : (nt - 1);
        const int ko = kn * 32;
        const int nb = (kt + 2) % 3;
        gl_lds16(gA + ko, &Ash[nb][t * 8]);
        gl_lds16(gB + ko, &Bsh[nb][t * 8]);
    }
    // drain before endpgm (pending LDS-DMA must not outlive the block's LDS)
    asm volatile("s_waitcnt vmcnt(0)" ::: "memory");

    // ---- epilogue: per-row sum of gelu(c + b1)*W2 over this wave's 64 cols ----
    float b1v[4], w2v[4];
    #pragma unroll
    for (int nf = 0; nf < 4; ++nf) {
        const int n = n0 + wc * 64 + nf * 16 + ln15;
        b1v[nf] = b1[n];
        w2v[nf] = W2[n];
    }
    #pragma unroll
    for (int mf = 0; mf < 2; ++mf)
        #pragma unroll
        for (int j = 0; j < 4; ++j) {
            float s = 0.f;
            #pragma unroll
            for (int nf = 0; nf < 4; ++nf) {
                float c = acc[mf][nf][j] + b1v[nf];
                s += gelu_f(c) * w2v[nf];
            }
            s += __shfl_xor(s, 1);
            s += __shfl_xor(s, 2);
            s += __shfl_xor(s, 4);
            s += __shfl_xor(s, 8);
            if (ln15 == 0) {
                const int m = m0 + wr * 32 + mf * 16 + lg * 4 + j;
                partial[(size_t)m * NT2 + blockIdx.y * 2 + wc] = s;
            }
        }
}

// ---------------------------------------------------------------------------
// K2a: M-parallel logits + probs. One thread per position; 12 contiguous
// partial loads. 64 blocks -> latency covered by TLP.
// ---------------------------------------------------------------------------
__global__ __launch_bounds__(256) void k2a_logits(
    const float* __restrict__ partial, const float* __restrict__ lengths,
    const float* __restrict__ b2p, float* __restrict__ logits,
    float* __restrict__ out_probs, int S)
{
    const int idx = blockIdx.x * 256 + threadIdx.x;
    const int b = idx / S, s = idx - b * S;
    float sum = b2p[0];
    #pragma unroll
    for (int jt = 0; jt < NT2; ++jt)
        sum += partial[(size_t)idx * NT2 + jt];
    logits[idx] = sum;
    const int len = (int)(lengths[b] * (float)S);
    out_probs[idx] = (s < len) ? 1.0f / (1.0f + expf(-sum)) : 0.0f;
}

// ---------------------------------------------------------------------------
// K2b: per-batch flags (logit>0, last_valid=1); scan -> bpos; nb/short/lens.
// ---------------------------------------------------------------------------
__global__ __launch_bounds__(256) void k2b_scan(
    const float* __restrict__ logits, const float* __restrict__ lengths,
    float* __restrict__ out_short, float* __restrict__ out_nb,
    float* __restrict__ out_lens, int* __restrict__ bpos,
    int* __restrict__ nb_arr, int S, int K)
{
    const int b = blockIdx.x;
    const int t = threadIdx.x;
    const int len = (int)(lengths[b] * (float)S);

    __shared__ int cnt[256];
    __shared__ int flags_s[2048];

    const int RP = S / 256;
    const int base_s = t * RP;
    int local = 0;
    #pragma unroll
    for (int r = 0; r < 8; ++r) {
        int s = base_s + r;
        bool v = (s < len);
        int f = (s == len - 1) ? 1 : ((v && logits[(size_t)b * S + s] > 0.0f) ? 1 : 0);
        flags_s[s] = f;
        local += f;
    }
    cnt[t] = local;
    __syncthreads();
    for (int off = 1; off < 256; off <<= 1) {
        int v = cnt[t];
        int u = (t >= off) ? cnt[t - off] : 0;
        __syncthreads();
        cnt[t] = v + u;
        __syncthreads();
    }
    int excl = cnt[t] - local;
    int total = cnt[255];
    for (int r = 0; r < RP; ++r) {
        int s = base_s + r;
        if (flags_s[s]) { bpos[b * S + excl] = s; ++excl; }
    }
    if (t == 0) {
        nb_arr[b] = total;
        float nbf = (float)total;
        float Kf  = (float)K;
        out_nb[b]   = nbf;
        out_lens[b] = (float)len;
        float sh;
        if (nbf >= Kf - 1.0f)      sh = 1.0f;
        else if (nbf > 0.0f)       sh = (nbf + 1.0f) / Kf;
        else                       sh = 0.0f;
        out_short[b] = sh;
    }
}

// ---------------------------------------------------------------------------
// K3 (bf16 source): segment-mean pooling from Xb. Block per (b,k).
// ---------------------------------------------------------------------------
__global__ __launch_bounds__(192) void k3_pool_bf(
    const __bf16* __restrict__ Xb, const int* __restrict__ bpos,
    const int* __restrict__ nb_arr, float* __restrict__ pooled,
    int S, int D, int K)
{
    const int bk = blockIdx.x;
    const int b  = bk / K;
    const int k  = bk - b * K;
    const int t  = threadIdx.x;
    const int nb = nb_arr[b];

    float4 acc = {0.f, 0.f, 0.f, 0.f};
    if (k < nb) {
        int start = (k == 0) ? 0 : (bpos[b * S + k - 1] + 1);
        int end   = bpos[b * S + k] + 1;
        float cntf = (float)(end - start);
        for (int s = start; s < end; ++s) {
            const ushort4 u = *(const ushort4*)&Xb[((size_t)b * S + s) * D + t * 4];
            acc.x += __builtin_bit_cast(float, (unsigned)u.x << 16);
            acc.y += __builtin_bit_cast(float, (unsigned)u.y << 16);
            acc.z += __builtin_bit_cast(float, (unsigned)u.z << 16);
            acc.w += __builtin_bit_cast(float, (unsigned)u.w << 16);
        }
        acc.x /= cntf; acc.y /= cntf; acc.z /= cntf; acc.w /= cntf;
    }
    *(float4*)&pooled[((size_t)b * K + k) * D + t * 4] = acc;
}

// ---------------------------------------------------------------------------
extern "C" void kernel_launch(void* const* d_in, const int* in_sizes, int n_in,
                              void* d_out, int out_size, void* d_ws, size_t ws_size,
                              hipStream_t stream) {
    const float* hidden  = (const float*)d_in[0];
    const float* lengths = (const float*)d_in[1];
    const float* W1      = (const float*)d_in[2];
    const float* b1      = (const float*)d_in[3];
    const float* W2      = (const float*)d_in[4];
    const float* b2      = (const float*)d_in[5];

    const int B = in_sizes[1];
    const int D = in_sizes[3];
    const int S = in_sizes[0] / (B * D);
    const int M = B * S;
    const int K = (out_size - B * S - 3 * B) / (B * D);

    float* out_pooled = (float*)d_out;
    float* out_probs  = out_pooled + (size_t)B * K * D;
    float* out_short  = out_probs + (size_t)B * S;
    float* out_nb     = out_short + B;
    float* out_lens   = out_nb + B;

    // d_ws: Xb (25.2 MB) + partial (786 KB) + logits + bpos + nb_arr
    // (rounds 11-12 ran this carve successfully on this harness)
    char* wsp = (char*)d_ws;
    __bf16* Xb = (__bf16*)wsp;    wsp += (size_t)M * D * sizeof(__bf16);
    float* partial = (float*)wsp; wsp += (size_t)M * NT2 * sizeof(float);
    float* logits  = (float*)wsp; wsp += (size_t)M * sizeof(float);
    int*   bpos    = (int*)wsp;   wsp += (size_t)M * sizeof(int);
    int*   nb_arr  = (int*)wsp;

    // bf16 W1^T lives in the pooled output region (K3 overwrites it at the end).
    __bf16* W1t = (__bf16*)out_pooled;

    dim3 gs(D / 32, D / 32);
    s0_w1t<<<gs, 256, 0, stream>>>(W1, W1t, D);

    const int n8 = M * D / 8;
    s0_xb<<<(n8 + 255) / 256, 256, 0, stream>>>(hidden, Xb, n8);

    dim3 g1(M / 128, D / 128);
    k1_p3<<<g1, 512, 0, stream>>>(Xb, W1t, b1, W2, partial, D);

    k2a_logits<<<M / 256, 256, 0, stream>>>(partial, lengths, b2, logits,
                                            out_probs, S);
    k2b_scan<<<B, 256, 0, stream>>>(logits, lengths, out_short, out_nb,
                                    out_lens, bpos, nb_arr, S, K);
    k3_pool_bf<<<B * K, D / 4, 0, stream>>>(Xb, bpos, nb_arr, out_pooled, S, D, K);
}